// Round 6
// baseline (378.537 us; speedup 1.0000x reference)
//
#include <hip/hip_runtime.h>

// CascadedAttentionCell: B=64, T=512, D=1024, OUT=1024 (all fp32 in/out)
//   WaS = prev@Wa + Ba;  UaH = inputs@Ua (68.7 GFLOP, fp16 MFMA);
//   scores = relu(tanh(UaH+WaS+Ba)@Va); sm = softmax_T; out = sum_t inputs*sm
// R8: m97-structure for B. R2/R3/R5/R7 (4 structures: barriers/no-barriers/
// ring/occupancy) ALL pin at 146-168us, MfmaUtil 18-19% == exactly
// (MFMA work 27.3us)/dur -> waves stalled 80% regardless. Invariants removed:
//  (a) HBM A-staging serialized inside the kernel -> now only 3 discrete
//      stage points (pass-outer, halves [0,1] then [1,0]; pass-2 A hits L3);
//  (b) per-wave global B loads behind conditionals in the K-loop -> B now
//      LDS-double-buffered via global_load_lds(16B) (async, no data VGPRs),
//      issued at chunk start, drained by the next __syncthreads ~500cy later.
// K-loop now touches ONLY LDS + L2-prefetch. acc[2][2]=64 AGPR, ~120 regs,
// launch_bounds(512,2): no spill. LDS 64K A + 2x32K B = 128.25 KiB.

#define NBATCH 64
#define NT     512
#define NDIM   1024
#define NOUT   1024

typedef _Float16 h8 __attribute__((ext_vector_type(8)));
typedef _Float16 h4 __attribute__((ext_vector_type(4)));
typedef float f16v __attribute__((ext_vector_type(16)));

__device__ __forceinline__ float tanh_fast(float x) {
    float e = __expf(2.0f * x);
    return 1.0f - 2.0f * __builtin_amdgcn_rcpf(e + 1.0f);
}

// ---- K2a: pack Ua (fp32 [K=1024][N=1024]) into fp16 B-fragment order ----
// t = ((nt*64+ks)*64) + kg*32 + nn ; thread writes 8 contiguous fp16 (16 B).
__global__ __launch_bounds__(256) void k_pack_ua(const float* __restrict__ Ua,
                                                 _Float16* __restrict__ B16) {
    int t = blockIdx.x * 256 + threadIdx.x;   // 0..131071
    int nn = t & 31, kg = (t >> 5) & 1, ks = (t >> 6) & 63, nt = t >> 12;
    int n = (nt << 5) + nn;
    int kbase = (ks << 4) + (kg << 3);
    h8 v;
#pragma unroll
    for (int j = 0; j < 8; ++j) v[j] = (_Float16)Ua[(size_t)(kbase + j) * 1024 + n];
    *(h8*)(B16 + ((size_t)t << 3)) = v;
}

// ---- K1: WaS partials: part[oc][b][p] = sum_{o in chunk} ps[b][o]*Wa[o][p] ----
__global__ __launch_bounds__(256) void k_was_part(const float* __restrict__ ps,
                                                  const float* __restrict__ Wa,
                                                  float* __restrict__ part) {
    int oc = blockIdx.x, b = blockIdx.y, tid = threadIdx.x;
    const float4* Wa4 = (const float4*)Wa;
    const float* psb = ps + b * 1024;
    float4 acc = {0.f, 0.f, 0.f, 0.f};
    int o0 = oc * 64;
#pragma unroll 4
    for (int o = o0; o < o0 + 64; ++o) {
        float s = psb[o];
        float4 wv = Wa4[o * 256 + tid];
        acc.x += s * wv.x; acc.y += s * wv.y; acc.z += s * wv.z; acc.w += s * wv.w;
    }
    ((float4*)part)[((oc << 6) + b) * 256 + tid] = acc;
}

// ---- K1b: wsWaS[b][p] = Ba[p] + sum_oc part ----
__global__ __launch_bounds__(256) void k_was_reduce(const float* __restrict__ part,
                                                    const float* __restrict__ Ba,
                                                    float* __restrict__ wsWaS) {
    int b = blockIdx.x, tid = threadIdx.x;
    const float4* p4 = (const float4*)part;
    float4 acc = ((const float4*)Ba)[tid];
#pragma unroll
    for (int oc = 0; oc < 16; ++oc) {
        float4 v = p4[((oc << 6) + b) * 256 + tid];
        acc.x += v.x; acc.y += v.y; acc.z += v.z; acc.w += v.w;
    }
    ((float4*)wsWaS)[b * 256 + tid] = acc;
}

// ---- K3: fused  scores[r] = relu( sum_n tanh(UaH[r][n]+wsWaS[b][n]) * Va[n] ) ----
// 512 threads = 8 waves; pass p: wave wv owns cols [p*512+wv*64, +64), acc[2][2].
// A: 64 KiB LDS half-strip (R7-verified XOR swizzle), staged 3x total.
// B: LDS double-buffer, chunk = 2 k-steps x 512 cols (32 KiB), global_load_lds.
__global__ __launch_bounds__(512, 2) void k_fused_gemm(
    const float* __restrict__ inputs, const _Float16* __restrict__ B16,
    const float* __restrict__ wsWaS, const float* __restrict__ Va,
    float* __restrict__ scores)
{
    __shared__ _Float16 Ash[64 * 512];       // 64 KiB, rows 1024 B, swizzled
    __shared__ _Float16 Bsh[2][32 * 512];    // 2 x 32 KiB, fragment order
    __shared__ float scoreSh[64];
    const int tid = threadIdx.x;                 // 0..511
    const int lane = tid & 63, wv = tid >> 6;
    const int l31 = lane & 31, lhi = lane >> 5;
    const int r0 = blockIdx.x * 64;
    const int b = r0 >> 9;
    const int srow = tid >> 3, sq = tid & 7;     // A staging: 8 threads/row
    const int swz = (srow & 7) << 4;

    if (tid < 64) scoreSh[tid] = 0.0f;

    // stage A half h (k-elems [h*512, h*512+512)): fp32 HBM/L3 -> fp16 LDS
    auto stageA = [&](int h) {
        const float4* src = (const float4*)inputs +
                            (size_t)(r0 + srow) * 256 + (h << 7) + sq;
        char* rowb = (char*)Ash + srow * 1024;
#pragma unroll 8
        for (int jj = 0; jj < 16; ++jj) {
            float4 v = src[jj * 8];
            *(h4*)(rowb + ((64 * jj + 8 * sq) ^ swz)) =
                (h4){ (_Float16)v.x, (_Float16)v.y, (_Float16)v.z, (_Float16)v.w };
        }
    };
    // async-stage B chunk c (k-steps {2c,2c+1} x cols [p*512,+512)) into buf.
    // Wave wv covers nt_local {2wv,2wv+1}; 4 x 1KB issues; no data VGPRs.
    auto stageB = [&](int p, int c, int buf) {
#pragma unroll
        for (int i = 0; i < 2; ++i) {
#pragma unroll
            for (int ksl = 0; ksl < 2; ++ksl) {
                const int ntl = 2 * wv + i;
                const size_t goff =
                    (((size_t)(((p << 4) + ntl) * 64 + 2 * c + ksl)) << 9) + lane * 8;
                _Float16* dst = &Bsh[buf][(ntl * 2 + ksl) << 9];
                __builtin_amdgcn_global_load_lds(
                    (const __attribute__((address_space(1))) void*)(B16 + goff),
                    (__attribute__((address_space(3))) void*)dst, 16, 0, 0);
            }
        }
    };

    const int aswz = (l31 & 7) << 4;
    const char* a0b = (const char*)Ash + l31 * 1024;

    for (int p = 0; p < 2; ++p) {
        f16v acc[2][2];
#pragma unroll
        for (int rt = 0; rt < 2; ++rt)
#pragma unroll
            for (int ct = 0; ct < 2; ++ct)
#pragma unroll
                for (int e = 0; e < 16; ++e) acc[rt][ct][e] = 0.0f;

        if (p == 0) stageA(0);           // pass 1 starts on resident half 1
        stageB(p, p == 0 ? 0 : 16, 0);
        __syncthreads();                 // drains A ds_writes + B vmem->LDS

        int buf = 0;
        for (int cc = 0; cc < 32; ++cc) {
            const int c = (p == 0) ? cc : ((cc + 16) & 31);
            if (cc == 16) {              // switch A halves (prev barrier fenced)
                stageA(p == 0 ? 1 : 0);
                __syncthreads();
            }
            if (cc < 31) stageB(p, (p == 0) ? (cc + 1) : ((cc + 17) & 31), buf ^ 1);
            // compute chunk c from buf (LDS only)
#pragma unroll
            for (int ksl = 0; ksl < 2; ++ksl) {
                const int ks_h = (2 * c + ksl) & 31;
                const int arow = ((ks_h >> 2) << 7) +
                                 (((32 * (ks_h & 3)) + (lhi << 4)) ^ aswz);
                h8 a0 = *(const h8*)(a0b + arow);
                h8 a1 = *(const h8*)(a0b + 32768 + arow);
                h8 bf0 = *(const h8*)&Bsh[buf][(((wv << 2) + ksl) << 9) + lane * 8];
                h8 bf1 = *(const h8*)&Bsh[buf][(((wv << 2) + 2 + ksl) << 9) + lane * 8];
                acc[0][0] = __builtin_amdgcn_mfma_f32_32x32x16_f16(a0, bf0, acc[0][0], 0, 0, 0);
                acc[1][0] = __builtin_amdgcn_mfma_f32_32x32x16_f16(a1, bf0, acc[1][0], 0, 0, 0);
                acc[0][1] = __builtin_amdgcn_mfma_f32_32x32x16_f16(a0, bf1, acc[0][1], 0, 0, 0);
                acc[1][1] = __builtin_amdgcn_mfma_f32_32x32x16_f16(a1, bf1, acc[1][1], 0, 0, 0);
            }
            __syncthreads();             // next buf staged; this buf reusable
            buf ^= 1;
        }

        // epilogue: tanh + Va dot, reduce over this pass's 64 cols per wave
        const int c0w = p * 512 + wv * 64;
        float wsv[2], vav[2];
#pragma unroll
        for (int ct = 0; ct < 2; ++ct) {
            int n = c0w + ct * 32 + l31;
            wsv[ct] = wsWaS[b * 1024 + n];
            vav[ct] = Va[n];
        }
#pragma unroll
        for (int rt = 0; rt < 2; ++rt) {
#pragma unroll
            for (int i = 0; i < 16; ++i) {
                float s = 0.0f;
#pragma unroll
                for (int ct = 0; ct < 2; ++ct)
                    s += tanh_fast(acc[rt][ct][i] + wsv[ct]) * vav[ct];
                s += __shfl_xor(s, 1);
                s += __shfl_xor(s, 2);
                s += __shfl_xor(s, 4);
                s += __shfl_xor(s, 8);
                s += __shfl_xor(s, 16);
                if (l31 == 0) {
                    int row = rt * 32 + (i & 3) + ((i >> 2) << 3) + (lhi << 2);
                    atomicAdd(&scoreSh[row], s);
                }
            }
        }
    }
    __syncthreads();
    if (tid < 64) scores[r0 + tid] = fmaxf(scoreSh[tid], 0.0f);
}

// ---- K4: softmax over T=512 per batch ----
__global__ __launch_bounds__(256) void k_softmax(const float* __restrict__ scores,
                                                 float* __restrict__ sm) {
    int b = blockIdx.x, tid = threadIdx.x;
    __shared__ float red[256];
    const float* sb = scores + b * 512;
    float s0 = sb[tid], s1 = sb[tid + 256];
    red[tid] = fmaxf(s0, s1);
    __syncthreads();
    for (int st = 128; st > 0; st >>= 1) {
        if (tid < st) red[tid] = fmaxf(red[tid], red[tid + st]);
        __syncthreads();
    }
    float m = red[0];
    __syncthreads();
    float e0 = __expf(s0 - m), e1 = __expf(s1 - m);
    red[tid] = e0 + e1;
    __syncthreads();
    for (int st = 128; st > 0; st >>= 1) {
        if (tid < st) red[tid] += red[tid + st];
        __syncthreads();
    }
    float inv = 1.0f / red[0];
    sm[b * 512 + tid] = e0 * inv;
    sm[b * 512 + 256 + tid] = e1 * inv;
}

// ---- K5: context partials over 32-timestep slices (16 slices -> 1024 blocks) ----
__global__ __launch_bounds__(256) void k_ctx_part(const float* __restrict__ inputs,
                                                  const float* __restrict__ sm,
                                                  float* __restrict__ part) {
    int ts = blockIdx.x, b = blockIdx.y, tid = threadIdx.x;
    const float4* inF4 = (const float4*)inputs;
    float4 acc = {0.f, 0.f, 0.f, 0.f};
    int t0 = ts * 32;
#pragma unroll 8
    for (int t = t0; t < t0 + 32; ++t) {
        float wgt = sm[b * 512 + t];
        float4 x = inF4[(size_t)(b * 512 + t) * 256 + tid];
        acc.x += wgt * x.x; acc.y += wgt * x.y; acc.z += wgt * x.z; acc.w += wgt * x.w;
    }
    ((float4*)part)[((ts << 6) + b) * 256 + tid] = acc;
}

// ---- K6: reduce 16 slices -> d_out ----
__global__ __launch_bounds__(256) void k_ctx_reduce(const float* __restrict__ part,
                                                    float* __restrict__ out) {
    int g = blockIdx.x * 256 + threadIdx.x;
    const float4* p4 = (const float4*)part;
    float4 acc = p4[g];
#pragma unroll
    for (int s = 1; s < 16; ++s) {
        float4 v = p4[s * 16384 + g];
        acc.x += v.x; acc.y += v.y; acc.z += v.z; acc.w += v.w;
    }
    ((float4*)out)[g] = acc;
}

extern "C" void kernel_launch(void* const* d_in, const int* in_sizes, int n_in,
                              void* d_out, int out_size, void* d_ws, size_t ws_size,
                              hipStream_t stream) {
    const float* inputs = (const float*)d_in[0];
    const float* prev   = (const float*)d_in[1];
    const float* Wa     = (const float*)d_in[2];
    const float* Ua     = (const float*)d_in[3];
    const float* Va     = (const float*)d_in[4];
    const float* Ba     = (const float*)d_in[5];
    float* out = (float*)d_out;

    char* ws = (char*)d_ws;
    _Float16* B16   = (_Float16*)(ws);               // 2 MB packed Ua [dead after fused]
    float* wasPart  = (float*)(ws + (2u << 20));     // 4 MB [dead after was_reduce]
    float* wsWaS    = (float*)(ws + (6u << 20));     // 256 KB
    float* scores   = (float*)(ws + (6u << 20) + (256u << 10));  // 128 KB
    float* sm       = (float*)(ws + (6u << 20) + (384u << 10));  // 128 KB
    float* ctxPart  = (float*)(ws);                  // 4 MB, overlays dead B16+wasPart

    hipLaunchKernelGGL(k_pack_ua,    dim3(512),    dim3(256), 0, stream, Ua, B16);
    hipLaunchKernelGGL(k_was_part,   dim3(16, 64), dim3(256), 0, stream, prev, Wa, wasPart);
    hipLaunchKernelGGL(k_was_reduce, dim3(64),     dim3(256), 0, stream, wasPart, Ba, wsWaS);
    hipLaunchKernelGGL(k_fused_gemm, dim3(512),    dim3(512), 0, stream, inputs, B16, wsWaS, Va, scores);
    hipLaunchKernelGGL(k_softmax,    dim3(64),     dim3(256), 0, stream, scores, sm);
    hipLaunchKernelGGL(k_ctx_part,   dim3(16, 64), dim3(256), 0, stream, inputs, sm, ctxPart);
    hipLaunchKernelGGL(k_ctx_reduce, dim3(64),     dim3(256), 0, stream, ctxPart, out);
}